// Round 1
// baseline (1193.133 us; speedup 1.0000x reference)
//
#include <hip/hip_runtime.h>

typedef unsigned short u16;
typedef u16 u16x8 __attribute__((ext_vector_type(8)));
typedef __bf16 bf16x8 __attribute__((ext_vector_type(8)));
typedef float f32x4 __attribute__((ext_vector_type(4)));

#define BB 16
#define TT 512
#define EE 768
#define HH 12
#define DD 64
#define LL 100
#define BT (BB*TT)             /* 8192 */
#define BTE ((size_t)BT*EE)    /* 6291456 */

__device__ __forceinline__ float bf2f(u16 u){
  union { float f; unsigned int i; } v; v.i = ((unsigned int)u) << 16; return v.f;
}
__device__ __forceinline__ u16 f2bf(float f){
  union { float f; unsigned int i; } v; v.f = f;
  unsigned int r = v.i + 0x7FFFu + ((v.i >> 16) & 1u);
  return (u16)(r >> 16);
}

// ---------------------------------------------------------------------------
// Prep: transpose + cast the 4 weight matrices (768x768 f32, row-major [K][N])
// into bf16 [N][K] so GEMM B-staging reads contiguous-K rows (MFMA B-frag needs
// 8 contiguous k per lane).
// ---------------------------------------------------------------------------
__global__ __launch_bounds__(256,1) void prep_w_kernel(
    const float* __restrict__ Wq, const float* __restrict__ Wk,
    const float* __restrict__ Wv, const float* __restrict__ Wo,
    u16* __restrict__ WT)
{
  int bx = blockIdx.x;
  int m  = bx / 144, t = bx % 144;
  int tr = t / 12,  tc = t % 12;
  const float* W = (m==0)?Wq : (m==1)?Wk : (m==2)?Wv : Wo;
  u16* dst = WT + (size_t)m * EE * EE;
  __shared__ float tile[64][65];
  int tid = threadIdx.x;
#pragma unroll
  for (int i=0;i<16;i++){
    int idx = tid + 256*i; int r = idx>>6, c = idx&63;
    tile[r][c] = W[(size_t)(tr*64+r)*EE + tc*64 + c];
  }
  __syncthreads();
#pragma unroll
  for (int i=0;i<16;i++){
    int idx = tid + 256*i; int r = idx>>6, c = idx&63;
    dst[(size_t)(tc*64+r)*EE + tr*64 + c] = f2bf(tile[c][r]);
  }
}

// ---------------------------------------------------------------------------
// K1: fused label cross-attention. One block = 16 consecutive (b,t) rows.
//  scores[l] = x . te[l] ; att = softmax ; fle = att @ te
//  writes: scores (f32, d_out tail), h_truth=x+fle (bf16), h_unknown=x+tp (bf16)
// ---------------------------------------------------------------------------
__global__ __launch_bounds__(256,1) void label_attn_kernel(
    const float* __restrict__ X, const float* __restrict__ TE,
    const float* __restrict__ tp, float* __restrict__ scores_out,
    u16* __restrict__ HT, u16* __restrict__ HU)
{
  __shared__ float xs[16][772];      // +4 pad: 16 rows hit 2-way banks max
  __shared__ float sc[16][100];
  __shared__ float att[16][100];
  int r0  = blockIdx.x * 16;
  int tid = threadIdx.x;

  // load 16 rows of x (float4, coalesced)
#pragma unroll
  for (int i=0;i<12;i++){
    int idx = tid + 256*i;          // 3072 float4 units
    int row = idx/192, c4 = idx%192;
    *(float4*)&xs[row][c4*4] = *(const float4*)&X[(size_t)(r0+row)*EE + c4*4];
  }
  __syncthreads();

  // scores: pair p -> (l = p>>4, row = p&15); 16 lanes share l => te broadcast
  for (int i=0;i<7;i++){
    int p = tid + 256*i;
    if (p < 1600){
      int l = p>>4, row = p&15;
      float acc = 0.f;
      const float4* te4 = (const float4*)(TE + (size_t)l*EE);
#pragma unroll 4
      for (int k4=0;k4<192;k4++){
        float4 t  = te4[k4];
        float4 xv = *(const float4*)&xs[row][k4*4];
        acc += xv.x*t.x + xv.y*t.y + xv.z*t.z + xv.w*t.w;
      }
      sc[row][l] = acc;
      scores_out[(size_t)(r0+row)*LL + l] = acc;
    }
  }
  __syncthreads();

  // softmax over L=100 per row; 16 threads per row, shfl width 16
  {
    int row = tid>>4, sub = tid&15;
    float m = -1e30f;
    for (int l=sub; l<LL; l+=16) m = fmaxf(m, sc[row][l]);
#pragma unroll
    for (int o=8;o;o>>=1) m = fmaxf(m, __shfl_xor(m, o, 16));
    float ssum = 0.f;
    for (int l=sub; l<LL; l+=16){ float p = __expf(sc[row][l]-m); att[row][l] = p; ssum += p; }
#pragma unroll
    for (int o=8;o;o>>=1) ssum += __shfl_xor(ssum, o, 16);
    float inv = 1.f/ssum;
    for (int l=sub; l<LL; l+=16) att[row][l] *= inv;
  }
  __syncthreads();

  // fle: stream te once; 48 accumulators (16 rows x 3 cols per thread)
  float facc[16][3] = {};
  for (int l=0;l<LL;l++){
    float t0 = TE[(size_t)l*EE + tid];
    float t1 = TE[(size_t)l*EE + tid + 256];
    float t2 = TE[(size_t)l*EE + tid + 512];
#pragma unroll
    for (int row=0;row<16;row++){
      float a = att[row][l];
      facc[row][0] += a*t0; facc[row][1] += a*t1; facc[row][2] += a*t2;
    }
  }
  float tpv[3] = { tp[tid], tp[tid+256], tp[tid+512] };
#pragma unroll
  for (int row=0;row<16;row++){
#pragma unroll
    for (int j=0;j<3;j++){
      int e = tid + j*256;
      float x   = xs[row][e];
      size_t o  = (size_t)(r0+row)*EE + e;
      HT[o] = f2bf(x + facc[row][j]);
      HU[o] = f2bf(x + tpv[j]);
    }
  }
}

// ---------------------------------------------------------------------------
// bf16 MFMA GEMM: C[M][N] = A[M][K] @ W[K][N] + bias, W given pre-transposed
// as BT[N][K]. 128x128 tile, BK=32, 4 waves (2x2), 16x16x32 MFMA.
// A-frag: lane row = l&15, k = (l>>4)*8..+8 (contiguous)  -> ds_read_b128
// B-frag: lane col = l&15, k contiguous                    -> BT rows, same
// C/D   : col = l&15, row = (l>>4)*4 + reg                [m89-verified]
// ---------------------------------------------------------------------------
__global__ __launch_bounds__(256,1) void gemm_bf16_kernel(
    const u16* __restrict__ A, const u16* __restrict__ BTw,
    const float* __restrict__ bias, u16* __restrict__ C,
    int M, int N, int K)
{
  __shared__ u16 As[128*40];    // pad 32->40: 16B-aligned rows, <=2-way banks
  __shared__ u16 Bs[128*40];
  int nb = N >> 7;
  int m0 = (blockIdx.x / nb) << 7;
  int n0 = (blockIdx.x % nb) << 7;
  int tid  = threadIdx.x, lane = tid & 63, w = tid >> 6;
  int wm = (w >> 1) << 6, wn = (w & 1) << 6;
  int lr = lane & 15, lk = (lane >> 4) << 3;

  f32x4 acc[4][4] = {};

  for (int k0 = 0; k0 < K; k0 += 32){
    __syncthreads();
#pragma unroll
    for (int i=0;i<2;i++){
      int idx = tid + (i<<8);
      int row = idx >> 2, kq = (idx & 3) << 3;
      *(u16x8*)&As[row*40 + kq] = *(const u16x8*)&A  [(size_t)(m0+row)*K + k0 + kq];
      *(u16x8*)&Bs[row*40 + kq] = *(const u16x8*)&BTw[(size_t)(n0+row)*K + k0 + kq];
    }
    __syncthreads();
    bf16x8 af[4], bfr[4];
#pragma unroll
    for (int i=0;i<4;i++) af [i] = *(const bf16x8*)&As[(wm + i*16 + lr)*40 + lk];
#pragma unroll
    for (int j=0;j<4;j++) bfr[j] = *(const bf16x8*)&Bs[(wn + j*16 + lr)*40 + lk];
#pragma unroll
    for (int i=0;i<4;i++)
#pragma unroll
      for (int j=0;j<4;j++)
        acc[i][j] = __builtin_amdgcn_mfma_f32_16x16x32_bf16(af[i], bfr[j], acc[i][j], 0, 0, 0);
  }

  int rbase = (lane >> 4) << 2;
#pragma unroll
  for (int j=0;j<4;j++){
    int col = n0 + wn + j*16 + lr;
    float bv = bias[col];
#pragma unroll
    for (int i=0;i<4;i++){
#pragma unroll
      for (int r=0;r<4;r++){
        int row = m0 + wm + i*16 + rbase + r;
        C[(size_t)row*N + col] = f2bf(acc[i][j][r] + bv);
      }
    }
  }
}

// ---------------------------------------------------------------------------
// K4: two-stream masked attention, f32 flash-style, one THREAD per q-row.
// Block = 128 threads = 128 q rows of one (b,h). K/V staged per 16-row tile
// into LDS as f32; all lanes read the same LDS address (pure broadcast, no
// conflicts). Softmax state entirely thread-local (no cross-lane reduce).
// ---------------------------------------------------------------------------
__global__ __launch_bounds__(128,1) void attn_kernel(
    const u16* __restrict__ Q, const u16* __restrict__ K,
    const u16* __restrict__ V, const float* __restrict__ mask,
    u16* __restrict__ CTX)
{
  __shared__ float Ks[16][64];
  __shared__ float Vs[16][64];
  int bx = blockIdx.x;
  int bh = bx >> 2, qq = (bx & 3) << 7;
  int b = bh / HH, h = bh % HH;
  int tid = threadIdx.x;
  int qrow = qq + tid;

  const u16* qp = Q + (size_t)(b*TT + qrow)*EE + h*DD;
  float q[64];
#pragma unroll
  for (int d8=0; d8<8; d8++){
    u16x8 v = *(const u16x8*)(qp + d8*8);
#pragma unroll
    for (int e=0;e<8;e++) q[d8*8+e] = bf2f(v[e]) * 0.125f;  // 1/sqrt(64)
  }
  float ctx[64];
#pragma unroll
  for (int d=0;d<64;d++) ctx[d] = 0.f;
  float mrun = -1e30f, lrun = 0.f;

  for (int kt=0; kt<32; kt++){
    int k0 = kt << 4;
    __syncthreads();
    {  // stage 16x64 K and V (bf16 -> f32)
      int kk = tid >> 3, c8 = (tid & 7) << 3;
      const u16* kp = K + (size_t)(b*TT + k0 + kk)*EE + h*DD + c8;
      const u16* vp = V + (size_t)(b*TT + k0 + kk)*EE + h*DD + c8;
      u16x8 kv = *(const u16x8*)kp;
      u16x8 vv = *(const u16x8*)vp;
#pragma unroll
      for (int e=0;e<8;e++){ Ks[kk][c8+e] = bf2f(kv[e]); Vs[kk][c8+e] = bf2f(vv[e]); }
    }
    __syncthreads();

    float s[16];
#pragma unroll
    for (int j=0;j<16;j++){
      float acc = 0.f;
#pragma unroll
      for (int d=0;d<64;d++) acc += q[d]*Ks[j][d];
      int kpos = k0 + j;
      float bias = (1.0f - mask[b*TT + kpos]) * (-1e9f);
      if (kpos == qrow) bias += -1e9f;
      s[j] = acc + bias;
    }
    float tm = s[0];
#pragma unroll
    for (int j=1;j<16;j++) tm = fmaxf(tm, s[j]);
    float mnew = fmaxf(mrun, tm);
    float scale = __expf(mrun - mnew);
    lrun *= scale;
#pragma unroll
    for (int d=0;d<64;d++) ctx[d] *= scale;
#pragma unroll
    for (int j=0;j<16;j++){
      float p = __expf(s[j] - mnew);
      lrun += p;
#pragma unroll
      for (int d=0;d<64;d++) ctx[d] += p * Vs[j][d];
    }
    mrun = mnew;
  }

  float inv = 1.0f / lrun;
  u16* op = CTX + (size_t)(b*TT + qrow)*EE + h*DD;
#pragma unroll
  for (int d8=0; d8<8; d8++){
    u16x8 o;
#pragma unroll
    for (int e=0;e<8;e++) o[e] = f2bf(ctx[d8*8+e]*inv);
    *(u16x8*)(op + d8*8) = o;
  }
}

// ---------------------------------------------------------------------------
// K5: LayerNorm(attn_out + h_unknown)*g + b  + h_truth  -> out (f32)
// One block per row.
// ---------------------------------------------------------------------------
__global__ __launch_bounds__(256,1) void ln_out_kernel(
    const u16* __restrict__ AO, const u16* __restrict__ HU,
    const u16* __restrict__ HT, const float* __restrict__ g,
    const float* __restrict__ bta, float* __restrict__ out)
{
  __shared__ float red[4];
  int r = blockIdx.x, tid = threadIdx.x;
  size_t base = (size_t)r*EE;
  float x[3];
#pragma unroll
  for (int j=0;j<3;j++){
    int e = tid + j*256;
    x[j] = bf2f(AO[base+e]) + bf2f(HU[base+e]);
  }
  float s = x[0]+x[1]+x[2];
#pragma unroll
  for (int o=32;o;o>>=1) s += __shfl_xor(s, o, 64);
  int w = tid>>6;
  if ((tid&63)==0) red[w] = s;
  __syncthreads();
  float mu = (red[0]+red[1]+red[2]+red[3]) * (1.0f/EE);
  __syncthreads();
  float d2 = 0.f;
#pragma unroll
  for (int j=0;j<3;j++){ float d = x[j]-mu; d2 += d*d; }
#pragma unroll
  for (int o=32;o;o>>=1) d2 += __shfl_xor(d2, o, 64);
  if ((tid&63)==0) red[w] = d2;
  __syncthreads();
  float var = (red[0]+red[1]+red[2]+red[3]) * (1.0f/EE);
  float rs = rsqrtf(var + 1e-12f);
#pragma unroll
  for (int j=0;j<3;j++){
    int e = tid + j*256;
    out[base+e] = (x[j]-mu)*rs*g[e] + bta[e] + bf2f(HT[base+e]);
  }
}

// ---------------------------------------------------------------------------
extern "C" void kernel_launch(void* const* d_in, const int* in_sizes, int n_in,
                              void* d_out, int out_size, void* d_ws, size_t ws_size,
                              hipStream_t stream)
{
  (void)in_sizes; (void)n_in; (void)out_size; (void)ws_size;
  const float* X    = (const float*)d_in[0];
  const float* mask = (const float*)d_in[1];
  const float* TE   = (const float*)d_in[2];
  const float* tp   = (const float*)d_in[3];
  const float* Wq   = (const float*)d_in[4];
  const float* bq   = (const float*)d_in[5];
  const float* Wk   = (const float*)d_in[6];
  const float* bk   = (const float*)d_in[7];
  const float* Wv   = (const float*)d_in[8];
  const float* bv   = (const float*)d_in[9];
  const float* Wo   = (const float*)d_in[10];
  const float* bo   = (const float*)d_in[11];
  const float* ln_g = (const float*)d_in[12];
  const float* ln_b = (const float*)d_in[13];

  float* out    = (float*)d_out;
  float* scores = out + BTE;

  char* ws = (char*)d_ws;
  const size_t BF = BTE*2;           // bytes of one [BT][E] bf16 buffer
  u16* HT   = (u16*)(ws);            // h_truth bf16
  u16* HU   = (u16*)(ws + BF);       // h_unknown bf16
  u16* WT   = (u16*)(ws + 2*BF);     // 4 x [768][768] bf16 (transposed)
  u16* Qb   = (u16*)(ws + 2*BF + (size_t)4*EE*EE*2);
  u16* Kb   = Qb  + BTE;
  u16* Vb   = Kb  + BTE;
  u16* CTXb = Vb  + BTE;
  u16* AOb  = CTXb + BTE;

  prep_w_kernel   <<<dim3(576),  dim3(256), 0, stream>>>(Wq, Wk, Wv, Wo, WT);
  label_attn_kernel<<<dim3(BT/16), dim3(256), 0, stream>>>(X, TE, tp, scores, HT, HU);

  const int M = BT, N = EE, K = EE;
  dim3 ggrid((M/128)*(N/128));
  gemm_bf16_kernel<<<ggrid, dim3(256), 0, stream>>>(HU, WT,             bq, Qb, M, N, K);
  gemm_bf16_kernel<<<ggrid, dim3(256), 0, stream>>>(HT, WT +   (size_t)EE*EE, bk, Kb, M, N, K);
  gemm_bf16_kernel<<<ggrid, dim3(256), 0, stream>>>(HT, WT + 2*(size_t)EE*EE, bv, Vb, M, N, K);

  attn_kernel<<<dim3(BB*HH*4), dim3(128), 0, stream>>>(Qb, Kb, Vb, mask, CTXb);

  gemm_bf16_kernel<<<ggrid, dim3(256), 0, stream>>>(CTXb, WT + 3*(size_t)EE*EE, bo, AOb, M, N, K);

  ln_out_kernel<<<dim3(BT), dim3(256), 0, stream>>>(AOb, HU, HT, ln_g, ln_b, out);
}

// Round 2
// 296.586 us; speedup vs baseline: 4.0229x; 4.0229x over previous
//
#include <hip/hip_runtime.h>

typedef unsigned short u16;
typedef u16 u16x8 __attribute__((ext_vector_type(8)));
typedef __bf16 bf16x8 __attribute__((ext_vector_type(8)));
typedef float f32x4 __attribute__((ext_vector_type(4)));

#define BB 16
#define TT 512
#define EE 768
#define HH 12
#define DD 64
#define LL 100
#define BT (BB*TT)             /* 8192 */
#define BTE ((size_t)BT*EE)    /* 6291456 */

__device__ __forceinline__ float bf2f(u16 u){
  union { float f; unsigned int i; } v; v.i = ((unsigned int)u) << 16; return v.f;
}
__device__ __forceinline__ u16 f2bf(float f){
  union { float f; unsigned int i; } v; v.f = f;
  unsigned int r = v.i + 0x7FFFu + ((v.i >> 16) & 1u);
  return (u16)(r >> 16);
}

// ---------------------------------------------------------------------------
// Prep: transpose + cast the 4 weight matrices (768x768 f32, row-major [K][N])
// into bf16 [N][K] so GEMM B-staging reads contiguous-K rows.
// ---------------------------------------------------------------------------
__global__ __launch_bounds__(256,1) void prep_w_kernel(
    const float* __restrict__ Wq, const float* __restrict__ Wk,
    const float* __restrict__ Wv, const float* __restrict__ Wo,
    u16* __restrict__ WT)
{
  int bx = blockIdx.x;
  int m  = bx / 144, t = bx % 144;
  int tr = t / 12,  tc = t % 12;
  const float* W = (m==0)?Wq : (m==1)?Wk : (m==2)?Wv : Wo;
  u16* dst = WT + (size_t)m * EE * EE;
  __shared__ float tile[64][65];
  int tid = threadIdx.x;
#pragma unroll
  for (int i=0;i<16;i++){
    int idx = tid + 256*i; int r = idx>>6, c = idx&63;
    tile[r][c] = W[(size_t)(tr*64+r)*EE + tc*64 + c];
  }
  __syncthreads();
#pragma unroll
  for (int i=0;i<16;i++){
    int idx = tid + 256*i; int r = idx>>6, c = idx&63;
    dst[(size_t)(tc*64+r)*EE + tr*64 + c] = f2bf(tile[c][r]);
  }
}

// ---------------------------------------------------------------------------
// K1: fused label cross-attention (unchanged; ~25us, revisit later)
// ---------------------------------------------------------------------------
__global__ __launch_bounds__(256,1) void label_attn_kernel(
    const float* __restrict__ X, const float* __restrict__ TE,
    const float* __restrict__ tp, float* __restrict__ scores_out,
    u16* __restrict__ HT, u16* __restrict__ HU)
{
  __shared__ float xs[16][772];
  __shared__ float sc[16][100];
  __shared__ float att[16][100];
  int r0  = blockIdx.x * 16;
  int tid = threadIdx.x;

#pragma unroll
  for (int i=0;i<12;i++){
    int idx = tid + 256*i;
    int row = idx/192, c4 = idx%192;
    *(float4*)&xs[row][c4*4] = *(const float4*)&X[(size_t)(r0+row)*EE + c4*4];
  }
  __syncthreads();

  for (int i=0;i<7;i++){
    int p = tid + 256*i;
    if (p < 1600){
      int l = p>>4, row = p&15;
      float acc = 0.f;
      const float4* te4 = (const float4*)(TE + (size_t)l*EE);
#pragma unroll 4
      for (int k4=0;k4<192;k4++){
        float4 t  = te4[k4];
        float4 xv = *(const float4*)&xs[row][k4*4];
        acc += xv.x*t.x + xv.y*t.y + xv.z*t.z + xv.w*t.w;
      }
      sc[row][l] = acc;
      scores_out[(size_t)(r0+row)*LL + l] = acc;
    }
  }
  __syncthreads();

  {
    int row = tid>>4, sub = tid&15;
    float m = -1e30f;
    for (int l=sub; l<LL; l+=16) m = fmaxf(m, sc[row][l]);
#pragma unroll
    for (int o=8;o;o>>=1) m = fmaxf(m, __shfl_xor(m, o, 16));
    float ssum = 0.f;
    for (int l=sub; l<LL; l+=16){ float p = __expf(sc[row][l]-m); att[row][l] = p; ssum += p; }
#pragma unroll
    for (int o=8;o;o>>=1) ssum += __shfl_xor(ssum, o, 16);
    float inv = 1.f/ssum;
    for (int l=sub; l<LL; l+=16) att[row][l] *= inv;
  }
  __syncthreads();

  float facc[16][3] = {};
  for (int l=0;l<LL;l++){
    float t0 = TE[(size_t)l*EE + tid];
    float t1 = TE[(size_t)l*EE + tid + 256];
    float t2 = TE[(size_t)l*EE + tid + 512];
#pragma unroll
    for (int row=0;row<16;row++){
      float a = att[row][l];
      facc[row][0] += a*t0; facc[row][1] += a*t1; facc[row][2] += a*t2;
    }
  }
  float tpv[3] = { tp[tid], tp[tid+256], tp[tid+512] };
#pragma unroll
  for (int row=0;row<16;row++){
#pragma unroll
    for (int j=0;j<3;j++){
      int e = tid + j*256;
      float x   = xs[row][e];
      size_t o  = (size_t)(r0+row)*EE + e;
      HT[o] = f2bf(x + facc[row][j]);
      HU[o] = f2bf(x + tpv[j]);
    }
  }
}

// ---------------------------------------------------------------------------
// bf16 MFMA GEMM (unchanged this round): C = A @ W + bias, W pre-transposed.
// ---------------------------------------------------------------------------
__global__ __launch_bounds__(256,1) void gemm_bf16_kernel(
    const u16* __restrict__ A, const u16* __restrict__ BTw,
    const float* __restrict__ bias, u16* __restrict__ C,
    int M, int N, int K)
{
  __shared__ u16 As[128*40];
  __shared__ u16 Bs[128*40];
  int nb = N >> 7;
  int m0 = (blockIdx.x / nb) << 7;
  int n0 = (blockIdx.x % nb) << 7;
  int tid  = threadIdx.x, lane = tid & 63, w = tid >> 6;
  int wm = (w >> 1) << 6, wn = (w & 1) << 6;
  int lr = lane & 15, lk = (lane >> 4) << 3;

  f32x4 acc[4][4] = {};

  for (int k0 = 0; k0 < K; k0 += 32){
    __syncthreads();
#pragma unroll
    for (int i=0;i<2;i++){
      int idx = tid + (i<<8);
      int row = idx >> 2, kq = (idx & 3) << 3;
      *(u16x8*)&As[row*40 + kq] = *(const u16x8*)&A  [(size_t)(m0+row)*K + k0 + kq];
      *(u16x8*)&Bs[row*40 + kq] = *(const u16x8*)&BTw[(size_t)(n0+row)*K + k0 + kq];
    }
    __syncthreads();
    bf16x8 af[4], bfr[4];
#pragma unroll
    for (int i=0;i<4;i++) af [i] = *(const bf16x8*)&As[(wm + i*16 + lr)*40 + lk];
#pragma unroll
    for (int j=0;j<4;j++) bfr[j] = *(const bf16x8*)&Bs[(wn + j*16 + lr)*40 + lk];
#pragma unroll
    for (int i=0;i<4;i++)
#pragma unroll
      for (int j=0;j<4;j++)
        acc[i][j] = __builtin_amdgcn_mfma_f32_16x16x32_bf16(af[i], bfr[j], acc[i][j], 0, 0, 0);
  }

  int rbase = (lane >> 4) << 2;
#pragma unroll
  for (int j=0;j<4;j++){
    int col = n0 + wn + j*16 + lr;
    float bv = bias[col];
#pragma unroll
    for (int i=0;i<4;i++){
#pragma unroll
      for (int r=0;r<4;r++){
        int row = m0 + wm + i*16 + rbase + r;
        C[(size_t)row*N + col] = f2bf(acc[i][j][r] + bv);
      }
    }
  }
}

// ---------------------------------------------------------------------------
// K4: MFMA flash attention. Block = one (b,h) x 128 q rows, 4 waves; each
// wave owns 32 q rows (2 x 16). K-loop over T in 64-row tiles.
//  S-frag   : mfma(Qfrag, Kfrag) -> S[q][k], col k = lane&15, row q = g*4+r
//  softmax  : row-max via shfl_xor width 16 (row is lane-group uniform);
//             l-sum kept lane-local (rescale factor row-uniform), reduced once
//  P        : bf16 via per-wave LDS round-trip -> A-frag layout
//  V        : stored transposed in LDS with k-block XOR swizzle so both the
//             transpose-writes and b128 B-frag reads are conflict-free:
//             VT[d][72] with k at ((k>>3) ^ ((d>>3)&7))*8 + (k&7)
// exp2-domain softmax: fold 0.125*log2e into scores.
// ---------------------------------------------------------------------------
__global__ __launch_bounds__(256,3) void attn_mfma_kernel(
    const u16* __restrict__ Q, const u16* __restrict__ K,
    const u16* __restrict__ V, const float* __restrict__ mask,
    u16* __restrict__ CTX)
{
  __shared__ u16 Ks[64*72];
  __shared__ u16 VT[64*72];
  __shared__ u16 Pl[4][32*72];
  __shared__ float MB[64];

  const float LOG2E = 1.44269504f;
  int bx = blockIdx.x;                 // 768 = (16*12) bh * 4 q-tiles
  int bh = bx >> 2, q0 = (bx & 3) << 7;
  int b = bh / HH, h = bh % HH;
  int tid = threadIdx.x, lane = tid & 63, w = tid >> 6;
  int l15 = lane & 15, g = lane >> 4;  // g in 0..3
  int wq0 = q0 + w*32;                 // wave's first q row within T
  size_t rowbase = (size_t)b*TT;
  u16* pw = &Pl[w][0];

  // Q fragments: rows wq0 + i*16 + l15, k = kk*32 + g*8 (A-frag layout)
  bf16x8 qf[2][2];
#pragma unroll
  for (int i=0;i<2;i++)
#pragma unroll
    for (int kk=0;kk<2;kk++)
      qf[i][kk] = *(const bf16x8*)&Q[(rowbase + wq0 + i*16 + l15)*EE + h*DD + kk*32 + g*8];

  f32x4 ctxf[2][4] = {};
  float mrun[2][4], lrun[2][4];
#pragma unroll
  for (int i=0;i<2;i++)
#pragma unroll
    for (int r=0;r<4;r++){ mrun[i][r] = -1e30f; lrun[i][r] = 0.f; }

  for (int k0=0; k0<TT; k0+=64){
    __syncthreads();
    // ---- stage K row-major + V transposed (swizzled) ----
#pragma unroll
    for (int u=0;u<2;u++){
      int unit = tid + (u<<8);                 // 0..511
      int row = unit >> 3, c8 = (unit & 7) << 3;
      size_t gsrc = (rowbase + k0 + row)*EE + h*DD + c8;
      u16x8 kv = *(const u16x8*)&K[gsrc];
      u16x8 vv = *(const u16x8*)&V[gsrc];
      *(u16x8*)&Ks[row*72 + c8] = kv;
      int kb8 = row >> 3, k7 = row & 7;
#pragma unroll
      for (int e=0;e<8;e++){
        int d = c8 + e;
        VT[d*72 + ((kb8 ^ ((d>>3)&7))<<3) + k7] = vv[e];
      }
    }
    if (tid < 64) MB[tid] = (1.0f - mask[b*TT + k0 + tid]) * (-1e9f * LOG2E);
    __syncthreads();

    // ---- S = Q K^T ----
    f32x4 s[2][4] = {};
#pragma unroll
    for (int kb=0;kb<4;kb++){
      bf16x8 kf0 = *(const bf16x8*)&Ks[(kb*16 + l15)*72 + g*8];
      bf16x8 kf1 = *(const bf16x8*)&Ks[(kb*16 + l15)*72 + 32 + g*8];
#pragma unroll
      for (int i=0;i<2;i++){
        s[i][kb] = __builtin_amdgcn_mfma_f32_16x16x32_bf16(qf[i][0], kf0, s[i][kb], 0,0,0);
        s[i][kb] = __builtin_amdgcn_mfma_f32_16x16x32_bf16(qf[i][1], kf1, s[i][kb], 0,0,0);
      }
    }

    // ---- scale + pad bias + diag bias (exp2 domain) ----
    const float QSC = 0.125f * LOG2E;
#pragma unroll
    for (int i=0;i<2;i++)
#pragma unroll
      for (int kb=0;kb<4;kb++){
        float mb = MB[kb*16 + l15];
#pragma unroll
        for (int r=0;r<4;r++) s[i][kb][r] = s[i][kb][r]*QSC + mb;
      }
    if ((k0 < wq0 + 32) && (k0 + 64 > wq0)){   // diag overlaps this wave?
#pragma unroll
      for (int i=0;i<2;i++){
        int qr = wq0 + i*16 + g*4;
#pragma unroll
        for (int kb=0;kb<4;kb++){
          int kpos = k0 + kb*16 + l15;
#pragma unroll
          for (int r=0;r<4;r++)
            if (kpos == qr + r) s[i][kb][r] -= 1e9f*LOG2E;
        }
      }
    }

    // ---- online softmax per q-row ----
#pragma unroll
    for (int i=0;i<2;i++){
#pragma unroll
      for (int r=0;r<4;r++){
        float tm = fmaxf(fmaxf(s[i][0][r], s[i][1][r]), fmaxf(s[i][2][r], s[i][3][r]));
        tm = fmaxf(tm, __shfl_xor(tm, 1, 16));
        tm = fmaxf(tm, __shfl_xor(tm, 2, 16));
        tm = fmaxf(tm, __shfl_xor(tm, 4, 16));
        tm = fmaxf(tm, __shfl_xor(tm, 8, 16));
        float mold = mrun[i][r];
        float mnew = fmaxf(mold, tm);
        float sc = exp2f(mold - mnew);
        mrun[i][r] = mnew;
        float ps = 0.f;
#pragma unroll
        for (int kb=0;kb<4;kb++){
          float p = exp2f(s[i][kb][r] - mnew);
          s[i][kb][r] = p;
          ps += p;
        }
        lrun[i][r] = lrun[i][r]*sc + ps;   // lane-local partial; reduced at end
#pragma unroll
        for (int dj=0;dj<4;dj++) ctxf[i][dj][r] *= sc;
      }
    }

    // ---- P -> LDS (bf16, A-frag friendly [q][k] stride 72) ----
#pragma unroll
    for (int i=0;i<2;i++)
#pragma unroll
      for (int kb=0;kb<4;kb++)
#pragma unroll
        for (int r=0;r<4;r++)
          pw[(i*16 + g*4 + r)*72 + kb*16 + l15] = f2bf(s[i][kb][r]);

    bf16x8 pa[2][2];
#pragma unroll
    for (int i=0;i<2;i++)
#pragma unroll
      for (int kk=0;kk<2;kk++)
        pa[i][kk] = *(const bf16x8*)&pw[(i*16 + l15)*72 + kk*32 + g*8];

    // ---- ctx += P V ----
#pragma unroll
    for (int dj=0;dj<4;dj++){
      int d = dj*16 + l15;
      int dsw = (d>>3)&7;
      bf16x8 v0 = *(const bf16x8*)&VT[d*72 + (((g  ) ^ dsw)<<3)];
      bf16x8 v1 = *(const bf16x8*)&VT[d*72 + (((g+4) ^ dsw)<<3)];
#pragma unroll
      for (int i=0;i<2;i++){
        ctxf[i][dj] = __builtin_amdgcn_mfma_f32_16x16x32_bf16(pa[i][0], v0, ctxf[i][dj], 0,0,0);
        ctxf[i][dj] = __builtin_amdgcn_mfma_f32_16x16x32_bf16(pa[i][1], v1, ctxf[i][dj], 0,0,0);
      }
    }
  }

  // ---- epilogue: reduce l, normalize, write via per-wave LDS ----
  float inv[2][4];
#pragma unroll
  for (int i=0;i<2;i++)
#pragma unroll
    for (int r=0;r<4;r++){
      float l = lrun[i][r];
      l += __shfl_xor(l, 1, 16);
      l += __shfl_xor(l, 2, 16);
      l += __shfl_xor(l, 4, 16);
      l += __shfl_xor(l, 8, 16);
      inv[i][r] = 1.0f / l;
    }
#pragma unroll
  for (int i=0;i<2;i++)
#pragma unroll
    for (int dj=0;dj<4;dj++)
#pragma unroll
      for (int r=0;r<4;r++)
        pw[(i*16 + g*4 + r)*64 + dj*16 + l15] = f2bf(ctxf[i][dj][r] * inv[i][r]);
#pragma unroll
  for (int t=0;t<4;t++){
    int row = lane >> 1, c = ((lane & 1)<<5) + t*8;
    *(u16x8*)&CTX[(rowbase + wq0 + row)*EE + h*DD + c] = *(const u16x8*)&pw[row*64 + c];
  }
}

// ---------------------------------------------------------------------------
// K5: LayerNorm(attn_out + h_unknown)*g + b + h_truth -> out (f32)
// ---------------------------------------------------------------------------
__global__ __launch_bounds__(256,1) void ln_out_kernel(
    const u16* __restrict__ AO, const u16* __restrict__ HU,
    const u16* __restrict__ HT, const float* __restrict__ g,
    const float* __restrict__ bta, float* __restrict__ out)
{
  __shared__ float red[4];
  int r = blockIdx.x, tid = threadIdx.x;
  size_t base = (size_t)r*EE;
  float x[3];
#pragma unroll
  for (int j=0;j<3;j++){
    int e = tid + j*256;
    x[j] = bf2f(AO[base+e]) + bf2f(HU[base+e]);
  }
  float s = x[0]+x[1]+x[2];
#pragma unroll
  for (int o=32;o;o>>=1) s += __shfl_xor(s, o, 64);
  int w = tid>>6;
  if ((tid&63)==0) red[w] = s;
  __syncthreads();
  float mu = (red[0]+red[1]+red[2]+red[3]) * (1.0f/EE);
  __syncthreads();
  float d2 = 0.f;
#pragma unroll
  for (int j=0;j<3;j++){ float d = x[j]-mu; d2 += d*d; }
#pragma unroll
  for (int o=32;o;o>>=1) d2 += __shfl_xor(d2, o, 64);
  if ((tid&63)==0) red[w] = d2;
  __syncthreads();
  float var = (red[0]+red[1]+red[2]+red[3]) * (1.0f/EE);
  float rs = rsqrtf(var + 1e-12f);
#pragma unroll
  for (int j=0;j<3;j++){
    int e = tid + j*256;
    out[base+e] = (x[j]-mu)*rs*g[e] + bta[e] + bf2f(HT[base+e]);
  }
}

// ---------------------------------------------------------------------------
extern "C" void kernel_launch(void* const* d_in, const int* in_sizes, int n_in,
                              void* d_out, int out_size, void* d_ws, size_t ws_size,
                              hipStream_t stream)
{
  (void)in_sizes; (void)n_in; (void)out_size; (void)ws_size;
  const float* X    = (const float*)d_in[0];
  const float* mask = (const float*)d_in[1];
  const float* TE   = (const float*)d_in[2];
  const float* tp   = (const float*)d_in[3];
  const float* Wq   = (const float*)d_in[4];
  const float* bq   = (const float*)d_in[5];
  const float* Wk   = (const float*)d_in[6];
  const float* bk   = (const float*)d_in[7];
  const float* Wv   = (const float*)d_in[8];
  const float* bv   = (const float*)d_in[9];
  const float* Wo   = (const float*)d_in[10];
  const float* bo   = (const float*)d_in[11];
  const float* ln_g = (const float*)d_in[12];
  const float* ln_b = (const float*)d_in[13];

  float* out    = (float*)d_out;
  float* scores = out + BTE;

  char* ws = (char*)d_ws;
  const size_t BF = BTE*2;           // bytes of one [BT][E] bf16 buffer
  u16* HT   = (u16*)(ws);
  u16* HU   = (u16*)(ws + BF);
  u16* WT   = (u16*)(ws + 2*BF);     // 4 x [768][768] bf16 (transposed)
  u16* Qb   = (u16*)(ws + 2*BF + (size_t)4*EE*EE*2);
  u16* Kb   = Qb  + BTE;
  u16* Vb   = Kb  + BTE;
  u16* CTXb = Vb  + BTE;
  u16* AOb  = CTXb + BTE;

  prep_w_kernel    <<<dim3(576),   dim3(256), 0, stream>>>(Wq, Wk, Wv, Wo, WT);
  label_attn_kernel<<<dim3(BT/16), dim3(256), 0, stream>>>(X, TE, tp, scores, HT, HU);

  const int M = BT, N = EE, K = EE;
  dim3 ggrid((M/128)*(N/128));
  gemm_bf16_kernel<<<ggrid, dim3(256), 0, stream>>>(HU, WT,                   bq, Qb, M, N, K);
  gemm_bf16_kernel<<<ggrid, dim3(256), 0, stream>>>(HT, WT +   (size_t)EE*EE, bk, Kb, M, N, K);
  gemm_bf16_kernel<<<ggrid, dim3(256), 0, stream>>>(HT, WT + 2*(size_t)EE*EE, bv, Vb, M, N, K);

  attn_mfma_kernel<<<dim3(BB*HH*4), dim3(256), 0, stream>>>(Qb, Kb, Vb, mask, CTXb);

  gemm_bf16_kernel<<<ggrid, dim3(256), 0, stream>>>(CTXb, WT + 3*(size_t)EE*EE, bo, AOb, M, N, K);

  ln_out_kernel<<<dim3(BT), dim3(256), 0, stream>>>(AOb, HU, HT, ln_g, ln_b, out);
}

// Round 3
// 206.662 us; speedup vs baseline: 5.7734x; 1.4351x over previous
//
#include <hip/hip_runtime.h>

typedef unsigned short u16;
typedef u16 u16x8 __attribute__((ext_vector_type(8)));
typedef __bf16 bf16x8 __attribute__((ext_vector_type(8)));
typedef float f32x4 __attribute__((ext_vector_type(4)));

#define BB 16
#define TT 512
#define EE 768
#define HH 12
#define DD 64
#define LL 100
#define BT (BB*TT)             /* 8192 */
#define BTE ((size_t)BT*EE)    /* 6291456 */

__device__ __forceinline__ float bf2f(u16 u){
  union { float f; unsigned int i; } v; v.i = ((unsigned int)u) << 16; return v.f;
}
__device__ __forceinline__ u16 f2bf(float f){
  union { float f; unsigned int i; } v; v.f = f;
  unsigned int r = v.i + 0x7FFFu + ((v.i >> 16) & 1u);
  return (u16)(r >> 16);
}

// ---------------------------------------------------------------------------
// Prep: transpose + cast the 4 weight matrices (768x768 f32, row-major [K][N])
// into bf16 [N][K] so GEMM B-staging reads contiguous-K rows.
// ---------------------------------------------------------------------------
__global__ __launch_bounds__(256,1) void prep_w_kernel(
    const float* __restrict__ Wq, const float* __restrict__ Wk,
    const float* __restrict__ Wv, const float* __restrict__ Wo,
    u16* __restrict__ WT)
{
  int bx = blockIdx.x;
  int m  = bx / 144, t = bx % 144;
  int tr = t / 12,  tc = t % 12;
  const float* W = (m==0)?Wq : (m==1)?Wk : (m==2)?Wv : Wo;
  u16* dst = WT + (size_t)m * EE * EE;
  __shared__ float tile[64][65];
  int tid = threadIdx.x;
#pragma unroll
  for (int i=0;i<16;i++){
    int idx = tid + 256*i; int r = idx>>6, c = idx&63;
    tile[r][c] = W[(size_t)(tr*64+r)*EE + tc*64 + c];
  }
  __syncthreads();
#pragma unroll
  for (int i=0;i<16;i++){
    int idx = tid + 256*i; int r = idx>>6, c = idx&63;
    dst[(size_t)(tc*64+r)*EE + tr*64 + c] = f2bf(tile[c][r]);
  }
}

// ---------------------------------------------------------------------------
// Prep TE: TEb[128][768] bf16 (label rows, zero rows >=100) for scores B-frags;
//          TEt[768][128] bf16 (transposed, zero cols >=100) for fle GEMM.
// ---------------------------------------------------------------------------
__global__ __launch_bounds__(128,1) void prep_te_kernel(
    const float* __restrict__ TE, u16* __restrict__ TEb, u16* __restrict__ TEt)
{
  int e   = blockIdx.x;   // 0..767
  int tid = threadIdx.x;  // 0..127
  u16 v = 0;
  if (tid < LL) v = f2bf(TE[(size_t)tid*EE + e]);
  TEt[(size_t)e*128 + tid] = v;
  if (e < 128){
#pragma unroll
    for (int k=tid; k<EE; k+=128)
      TEb[(size_t)e*EE + k] = (e < LL) ? f2bf(TE[(size_t)e*EE + k]) : (u16)0;
  }
}

// ---------------------------------------------------------------------------
// K1: label scores + softmax via MFMA. Block = 32 rows (2 waves x 16 rows),
// 256 blocks. S[32][112] = X[32][768] @ TEb^T via 16x16x32 MFMA (12 k-steps,
// X cast f32->bf16 during staging). Raw scores f32 written from C-frags;
// softmax in C-layout (row = g*4+r, col = nt*16+l15; row-max/sum = shfl_xor
// width 16); att bf16 [8192][128] emitted in fle-GEMM A-layout (cols>=100 = 0).
// ---------------------------------------------------------------------------
__global__ __launch_bounds__(128,4) void label_scores_kernel(
    const float* __restrict__ X, const u16* __restrict__ TEb,
    float* __restrict__ scores_out, u16* __restrict__ att)
{
  __shared__ u16 Xc[32*72];    // stride 72: 2-way banks max on b128 reads
  __shared__ u16 TEc[112*72];
  const float LOG2E = 1.44269504f;
  int m0 = blockIdx.x * 32;
  int tid = threadIdx.x, lane = tid & 63, w = tid >> 6;   // w in 0..1
  int l15 = lane & 15, g = lane >> 4;

  f32x4 s[7] = {};
  for (int k0=0; k0<EE; k0+=64){
    __syncthreads();
    // stage X chunk: 32 rows x 64 cols (256 units of 8)
#pragma unroll
    for (int u=0;u<2;u++){
      int unit = tid + u*128;
      int row = unit >> 3, c8 = (unit & 7) << 3;
      const float* src = &X[(size_t)(m0+row)*EE + k0 + c8];
      float4 a = *(const float4*)src, b = *(const float4*)(src+4);
      u16x8 o;
      o[0]=f2bf(a.x); o[1]=f2bf(a.y); o[2]=f2bf(a.z); o[3]=f2bf(a.w);
      o[4]=f2bf(b.x); o[5]=f2bf(b.y); o[6]=f2bf(b.z); o[7]=f2bf(b.w);
      *(u16x8*)&Xc[row*72 + c8] = o;
    }
    // stage TE chunk: 112 rows x 64 cols (896 units of 8), bf16 source
#pragma unroll
    for (int u=0;u<7;u++){
      int unit = tid + u*128;
      int l = unit >> 3, c8 = (unit & 7) << 3;
      *(u16x8*)&TEc[l*72 + c8] = *(const u16x8*)&TEb[(size_t)l*EE + k0 + c8];
    }
    __syncthreads();
    bf16x8 af0 = *(const bf16x8*)&Xc[(w*16 + l15)*72 + g*8];
    bf16x8 af1 = *(const bf16x8*)&Xc[(w*16 + l15)*72 + 32 + g*8];
#pragma unroll
    for (int nt=0;nt<7;nt++){
      bf16x8 b0 = *(const bf16x8*)&TEc[(nt*16 + l15)*72 + g*8];
      bf16x8 b1 = *(const bf16x8*)&TEc[(nt*16 + l15)*72 + 32 + g*8];
      s[nt] = __builtin_amdgcn_mfma_f32_16x16x32_bf16(af0, b0, s[nt], 0,0,0);
      s[nt] = __builtin_amdgcn_mfma_f32_16x16x32_bf16(af1, b1, s[nt], 0,0,0);
    }
  }

  int rowb = m0 + w*16 + g*4;
  // raw scores (f32, cols < 100)
#pragma unroll
  for (int nt=0;nt<7;nt++){
    int col = nt*16 + l15;
    if (col < LL){
#pragma unroll
      for (int r=0;r<4;r++)
        scores_out[(size_t)(rowb + r)*LL + col] = s[nt][r];
    }
  }
  // mask padded labels (only nt=6, l15>=4 -> col>=100)
  if (l15 >= 4){
#pragma unroll
    for (int r=0;r<4;r++) s[6][r] = -1e30f;
  }
  // softmax per row
  float inv[4];
#pragma unroll
  for (int r=0;r<4;r++){
    float tm = s[0][r];
#pragma unroll
    for (int nt=1;nt<7;nt++) tm = fmaxf(tm, s[nt][r]);
    tm = fmaxf(tm, __shfl_xor(tm, 1, 16));
    tm = fmaxf(tm, __shfl_xor(tm, 2, 16));
    tm = fmaxf(tm, __shfl_xor(tm, 4, 16));
    tm = fmaxf(tm, __shfl_xor(tm, 8, 16));
    float ps = 0.f;
#pragma unroll
    for (int nt=0;nt<7;nt++){
      float p = exp2f((s[nt][r] - tm) * LOG2E);
      s[nt][r] = p; ps += p;
    }
    ps += __shfl_xor(ps, 1, 16);
    ps += __shfl_xor(ps, 2, 16);
    ps += __shfl_xor(ps, 4, 16);
    ps += __shfl_xor(ps, 8, 16);
    inv[r] = 1.f/ps;
  }
  // att bf16 [8192][128]
#pragma unroll
  for (int nt=0;nt<7;nt++){
    int col = nt*16 + l15;
#pragma unroll
    for (int r=0;r<4;r++)
      att[(size_t)(rowb + r)*128 + col] = f2bf(s[nt][r] * inv[r]);
  }
  {
    int col = 112 + l15;
#pragma unroll
    for (int r=0;r<4;r++) att[(size_t)(rowb + r)*128 + col] = 0;
  }
}

// ---------------------------------------------------------------------------
// bf16 MFMA GEMM: C[M][N] = A[M][K] @ W[K][N], W pre-transposed as BTw[N][K].
// 128x128 tile, BK=32, 4 waves (2x2), 16x16x32 MFMA.
// MODE 0: C = bf16(acc + bias[col])
// MODE 1: fle epilogue — HT = bf16(X+acc), HU = bf16(X+tp[col]); C unused.
// ---------------------------------------------------------------------------
template<int MODE>
__global__ __launch_bounds__(256,1) void gemm_bf16_kernel(
    const u16* __restrict__ A, const u16* __restrict__ BTw,
    const float* __restrict__ bias, u16* __restrict__ C,
    const float* __restrict__ Xf, const float* __restrict__ tp,
    u16* __restrict__ HT, u16* __restrict__ HU,
    int M, int N, int K)
{
  __shared__ u16 As[128*40];
  __shared__ u16 Bs[128*40];
  int nb = N >> 7;
  int m0 = (blockIdx.x / nb) << 7;
  int n0 = (blockIdx.x % nb) << 7;
  int tid  = threadIdx.x, lane = tid & 63, w = tid >> 6;
  int wm = (w >> 1) << 6, wn = (w & 1) << 6;
  int lr = lane & 15, lk = (lane >> 4) << 3;

  f32x4 acc[4][4] = {};

  for (int k0 = 0; k0 < K; k0 += 32){
    __syncthreads();
#pragma unroll
    for (int i=0;i<2;i++){
      int idx = tid + (i<<8);
      int row = idx >> 2, kq = (idx & 3) << 3;
      *(u16x8*)&As[row*40 + kq] = *(const u16x8*)&A  [(size_t)(m0+row)*K + k0 + kq];
      *(u16x8*)&Bs[row*40 + kq] = *(const u16x8*)&BTw[(size_t)(n0+row)*K + k0 + kq];
    }
    __syncthreads();
    bf16x8 af[4], bfr[4];
#pragma unroll
    for (int i=0;i<4;i++) af [i] = *(const bf16x8*)&As[(wm + i*16 + lr)*40 + lk];
#pragma unroll
    for (int j=0;j<4;j++) bfr[j] = *(const bf16x8*)&Bs[(wn + j*16 + lr)*40 + lk];
#pragma unroll
    for (int i=0;i<4;i++)
#pragma unroll
      for (int j=0;j<4;j++)
        acc[i][j] = __builtin_amdgcn_mfma_f32_16x16x32_bf16(af[i], bfr[j], acc[i][j], 0, 0, 0);
  }

  int rbase = (lane >> 4) << 2;
#pragma unroll
  for (int j=0;j<4;j++){
    int col = n0 + wn + j*16 + lr;
    if (MODE == 0){
      float bv = bias[col];
#pragma unroll
      for (int i=0;i<4;i++){
#pragma unroll
        for (int r=0;r<4;r++){
          int row = m0 + wm + i*16 + rbase + r;
          C[(size_t)row*N + col] = f2bf(acc[i][j][r] + bv);
        }
      }
    } else {
      float tpv = tp[col];
#pragma unroll
      for (int i=0;i<4;i++){
#pragma unroll
        for (int r=0;r<4;r++){
          int row = m0 + wm + i*16 + rbase + r;
          float x = Xf[(size_t)row*EE + col];
          HT[(size_t)row*EE + col] = f2bf(x + acc[i][j][r]);
          HU[(size_t)row*EE + col] = f2bf(x + tpv);
        }
      }
    }
  }
}

// ---------------------------------------------------------------------------
// K4: MFMA flash attention (unchanged).
// ---------------------------------------------------------------------------
__global__ __launch_bounds__(256,3) void attn_mfma_kernel(
    const u16* __restrict__ Q, const u16* __restrict__ K,
    const u16* __restrict__ V, const float* __restrict__ mask,
    u16* __restrict__ CTX)
{
  __shared__ u16 Ks[64*72];
  __shared__ u16 VT[64*72];
  __shared__ u16 Pl[4][32*72];
  __shared__ float MB[64];

  const float LOG2E = 1.44269504f;
  int bx = blockIdx.x;
  int bh = bx >> 2, q0 = (bx & 3) << 7;
  int b = bh / HH, h = bh % HH;
  int tid = threadIdx.x, lane = tid & 63, w = tid >> 6;
  int l15 = lane & 15, g = lane >> 4;
  int wq0 = q0 + w*32;
  size_t rowbase = (size_t)b*TT;
  u16* pw = &Pl[w][0];

  bf16x8 qf[2][2];
#pragma unroll
  for (int i=0;i<2;i++)
#pragma unroll
    for (int kk=0;kk<2;kk++)
      qf[i][kk] = *(const bf16x8*)&Q[(rowbase + wq0 + i*16 + l15)*EE + h*DD + kk*32 + g*8];

  f32x4 ctxf[2][4] = {};
  float mrun[2][4], lrun[2][4];
#pragma unroll
  for (int i=0;i<2;i++)
#pragma unroll
    for (int r=0;r<4;r++){ mrun[i][r] = -1e30f; lrun[i][r] = 0.f; }

  for (int k0=0; k0<TT; k0+=64){
    __syncthreads();
#pragma unroll
    for (int u=0;u<2;u++){
      int unit = tid + (u<<8);
      int row = unit >> 3, c8 = (unit & 7) << 3;
      size_t gsrc = (rowbase + k0 + row)*EE + h*DD + c8;
      u16x8 kv = *(const u16x8*)&K[gsrc];
      u16x8 vv = *(const u16x8*)&V[gsrc];
      *(u16x8*)&Ks[row*72 + c8] = kv;
      int kb8 = row >> 3, k7 = row & 7;
#pragma unroll
      for (int e=0;e<8;e++){
        int d = c8 + e;
        VT[d*72 + ((kb8 ^ ((d>>3)&7))<<3) + k7] = vv[e];
      }
    }
    if (tid < 64) MB[tid] = (1.0f - mask[b*TT + k0 + tid]) * (-1e9f * LOG2E);
    __syncthreads();

    f32x4 s[2][4] = {};
#pragma unroll
    for (int kb=0;kb<4;kb++){
      bf16x8 kf0 = *(const bf16x8*)&Ks[(kb*16 + l15)*72 + g*8];
      bf16x8 kf1 = *(const bf16x8*)&Ks[(kb*16 + l15)*72 + 32 + g*8];
#pragma unroll
      for (int i=0;i<2;i++){
        s[i][kb] = __builtin_amdgcn_mfma_f32_16x16x32_bf16(qf[i][0], kf0, s[i][kb], 0,0,0);
        s[i][kb] = __builtin_amdgcn_mfma_f32_16x16x32_bf16(qf[i][1], kf1, s[i][kb], 0,0,0);
      }
    }

    const float QSC = 0.125f * LOG2E;
#pragma unroll
    for (int i=0;i<2;i++)
#pragma unroll
      for (int kb=0;kb<4;kb++){
        float mb = MB[kb*16 + l15];
#pragma unroll
        for (int r=0;r<4;r++) s[i][kb][r] = s[i][kb][r]*QSC + mb;
      }
    if ((k0 < wq0 + 32) && (k0 + 64 > wq0)){
#pragma unroll
      for (int i=0;i<2;i++){
        int qr = wq0 + i*16 + g*4;
#pragma unroll
        for (int kb=0;kb<4;kb++){
          int kpos = k0 + kb*16 + l15;
#pragma unroll
          for (int r=0;r<4;r++)
            if (kpos == qr + r) s[i][kb][r] -= 1e9f*LOG2E;
        }
      }
    }

#pragma unroll
    for (int i=0;i<2;i++){
#pragma unroll
      for (int r=0;r<4;r++){
        float tm = fmaxf(fmaxf(s[i][0][r], s[i][1][r]), fmaxf(s[i][2][r], s[i][3][r]));
        tm = fmaxf(tm, __shfl_xor(tm, 1, 16));
        tm = fmaxf(tm, __shfl_xor(tm, 2, 16));
        tm = fmaxf(tm, __shfl_xor(tm, 4, 16));
        tm = fmaxf(tm, __shfl_xor(tm, 8, 16));
        float mold = mrun[i][r];
        float mnew = fmaxf(mold, tm);
        float sc = exp2f(mold - mnew);
        mrun[i][r] = mnew;
        float ps = 0.f;
#pragma unroll
        for (int kb=0;kb<4;kb++){
          float p = exp2f(s[i][kb][r] - mnew);
          s[i][kb][r] = p;
          ps += p;
        }
        lrun[i][r] = lrun[i][r]*sc + ps;
#pragma unroll
        for (int dj=0;dj<4;dj++) ctxf[i][dj][r] *= sc;
      }
    }

#pragma unroll
    for (int i=0;i<2;i++)
#pragma unroll
      for (int kb=0;kb<4;kb++)
#pragma unroll
        for (int r=0;r<4;r++)
          pw[(i*16 + g*4 + r)*72 + kb*16 + l15] = f2bf(s[i][kb][r]);

    bf16x8 pa[2][2];
#pragma unroll
    for (int i=0;i<2;i++)
#pragma unroll
      for (int kk=0;kk<2;kk++)
        pa[i][kk] = *(const bf16x8*)&pw[(i*16 + l15)*72 + kk*32 + g*8];

#pragma unroll
    for (int dj=0;dj<4;dj++){
      int d = dj*16 + l15;
      int dsw = (d>>3)&7;
      bf16x8 v0 = *(const bf16x8*)&VT[d*72 + (((g  ) ^ dsw)<<3)];
      bf16x8 v1 = *(const bf16x8*)&VT[d*72 + (((g+4) ^ dsw)<<3)];
#pragma unroll
      for (int i=0;i<2;i++){
        ctxf[i][dj] = __builtin_amdgcn_mfma_f32_16x16x32_bf16(pa[i][0], v0, ctxf[i][dj], 0,0,0);
        ctxf[i][dj] = __builtin_amdgcn_mfma_f32_16x16x32_bf16(pa[i][1], v1, ctxf[i][dj], 0,0,0);
      }
    }
  }

  float inv[2][4];
#pragma unroll
  for (int i=0;i<2;i++)
#pragma unroll
    for (int r=0;r<4;r++){
      float l = lrun[i][r];
      l += __shfl_xor(l, 1, 16);
      l += __shfl_xor(l, 2, 16);
      l += __shfl_xor(l, 4, 16);
      l += __shfl_xor(l, 8, 16);
      inv[i][r] = 1.0f / l;
    }
#pragma unroll
  for (int i=0;i<2;i++)
#pragma unroll
    for (int dj=0;dj<4;dj++)
#pragma unroll
      for (int r=0;r<4;r++)
        pw[(i*16 + g*4 + r)*64 + dj*16 + l15] = f2bf(ctxf[i][dj][r] * inv[i][r]);
#pragma unroll
  for (int t=0;t<4;t++){
    int row = lane >> 1, c = ((lane & 1)<<5) + t*8;
    *(u16x8*)&CTX[(rowbase + wq0 + row)*EE + h*DD + c] = *(const u16x8*)&pw[row*64 + c];
  }
}

// ---------------------------------------------------------------------------
// K5: LayerNorm(attn_out + h_unknown)*g + b + h_truth -> out (f32)
// ---------------------------------------------------------------------------
__global__ __launch_bounds__(256,1) void ln_out_kernel(
    const u16* __restrict__ AO, const u16* __restrict__ HU,
    const u16* __restrict__ HT, const float* __restrict__ g,
    const float* __restrict__ bta, float* __restrict__ out)
{
  __shared__ float red[4];
  int r = blockIdx.x, tid = threadIdx.x;
  size_t base = (size_t)r*EE;
  float x[3];
#pragma unroll
  for (int j=0;j<3;j++){
    int e = tid + j*256;
    x[j] = bf2f(AO[base+e]) + bf2f(HU[base+e]);
  }
  float s = x[0]+x[1]+x[2];
#pragma unroll
  for (int o=32;o;o>>=1) s += __shfl_xor(s, o, 64);
  int w = tid>>6;
  if ((tid&63)==0) red[w] = s;
  __syncthreads();
  float mu = (red[0]+red[1]+red[2]+red[3]) * (1.0f/EE);
  __syncthreads();
  float d2 = 0.f;
#pragma unroll
  for (int j=0;j<3;j++){ float d = x[j]-mu; d2 += d*d; }
#pragma unroll
  for (int o=32;o;o>>=1) d2 += __shfl_xor(d2, o, 64);
  if ((tid&63)==0) red[w] = d2;
  __syncthreads();
  float var = (red[0]+red[1]+red[2]+red[3]) * (1.0f/EE);
  float rs = rsqrtf(var + 1e-12f);
#pragma unroll
  for (int j=0;j<3;j++){
    int e = tid + j*256;
    out[base+e] = (x[j]-mu)*rs*g[e] + bta[e] + bf2f(HT[base+e]);
  }
}

// ---------------------------------------------------------------------------
extern "C" void kernel_launch(void* const* d_in, const int* in_sizes, int n_in,
                              void* d_out, int out_size, void* d_ws, size_t ws_size,
                              hipStream_t stream)
{
  (void)in_sizes; (void)n_in; (void)out_size; (void)ws_size;
  const float* X    = (const float*)d_in[0];
  const float* mask = (const float*)d_in[1];
  const float* TE   = (const float*)d_in[2];
  const float* tp   = (const float*)d_in[3];
  const float* Wq   = (const float*)d_in[4];
  const float* bq   = (const float*)d_in[5];
  const float* Wk   = (const float*)d_in[6];
  const float* bk   = (const float*)d_in[7];
  const float* Wv   = (const float*)d_in[8];
  const float* bv   = (const float*)d_in[9];
  const float* Wo   = (const float*)d_in[10];
  const float* bo   = (const float*)d_in[11];
  const float* ln_g = (const float*)d_in[12];
  const float* ln_b = (const float*)d_in[13];

  float* out    = (float*)d_out;
  float* scores = out + BTE;

  char* ws = (char*)d_ws;
  const size_t BF = BTE*2;           // bytes of one [BT][E] bf16 buffer
  u16* HT   = (u16*)(ws);
  u16* HU   = (u16*)(ws + BF);
  u16* WT   = (u16*)(ws + 2*BF);     // 4 x [768][768] bf16 (transposed)
  u16* Qb   = (u16*)(ws + 2*BF + (size_t)4*EE*EE*2);
  u16* Kb   = Qb  + BTE;
  u16* Vb   = Kb  + BTE;
  u16* CTXb = Vb  + BTE;
  u16* AOb  = CTXb + BTE;
  u16* ATT  = AOb + BTE;                       // [8192][128] bf16
  u16* TEb  = ATT + (size_t)BT*128;            // [128][768] bf16
  u16* TEt  = TEb + (size_t)128*EE;            // [768][128] bf16

  prep_w_kernel <<<dim3(576), dim3(256), 0, stream>>>(Wq, Wk, Wv, Wo, WT);
  prep_te_kernel<<<dim3(768), dim3(128), 0, stream>>>(TE, TEb, TEt);

  label_scores_kernel<<<dim3(BT/32), dim3(128), 0, stream>>>(X, TEb, scores, ATT);

  // fle GEMM + fused HT/HU epilogue: M=8192, N=768, K=128
  gemm_bf16_kernel<1><<<dim3((BT/128)*(EE/128)), dim3(256), 0, stream>>>(
      ATT, TEt, nullptr, nullptr, X, tp, HT, HU, BT, EE, 128);

  const int M = BT, N = EE, K = EE;
  dim3 ggrid((M/128)*(N/128));
  gemm_bf16_kernel<0><<<ggrid, dim3(256), 0, stream>>>(
      HU, WT,                   bq, Qb, nullptr, nullptr, nullptr, nullptr, M, N, K);
  gemm_bf16_kernel<0><<<ggrid, dim3(256), 0, stream>>>(
      HT, WT +   (size_t)EE*EE, bk, Kb, nullptr, nullptr, nullptr, nullptr, M, N, K);
  gemm_bf16_kernel<0><<<ggrid, dim3(256), 0, stream>>>(
      HT, WT + 2*(size_t)EE*EE, bv, Vb, nullptr, nullptr, nullptr, nullptr, M, N, K);

  attn_mfma_kernel<<<dim3(BB*HH*4), dim3(256), 0, stream>>>(Qb, Kb, Vb, mask, CTXb);

  gemm_bf16_kernel<0><<<ggrid, dim3(256), 0, stream>>>(
      CTXb, WT + 3*(size_t)EE*EE, bo, AOb, nullptr, nullptr, nullptr, nullptr, M, N, K);

  ln_out_kernel<<<dim3(BT), dim3(256), 0, stream>>>(AOb, HU, HT, ln_g, ln_b, out);
}

// Round 4
// 158.006 us; speedup vs baseline: 7.5512x; 1.3079x over previous
//
#include <hip/hip_runtime.h>

typedef unsigned short u16;
typedef u16 u16x8 __attribute__((ext_vector_type(8)));
typedef __bf16 bf16x8 __attribute__((ext_vector_type(8)));
typedef float f32x4 __attribute__((ext_vector_type(4)));

#define BB 16
#define TT 512
#define EE 768
#define HH 12
#define DD 64
#define LL 100
#define BT (BB*TT)             /* 8192 */
#define BTE ((size_t)BT*EE)    /* 6291456 */

__device__ __forceinline__ float bf2f(u16 u){
  union { float f; unsigned int i; } v; v.i = ((unsigned int)u) << 16; return v.f;
}
__device__ __forceinline__ u16 f2bf(float f){
  union { float f; unsigned int i; } v; v.f = f;
  unsigned int r = v.i + 0x7FFFu + ((v.i >> 16) & 1u);
  return (u16)(r >> 16);
}

// async 16B global->LDS (DMA, no VGPR round-trip). LDS dest is wave-uniform
// base + lane*16; global src is per-lane.
__device__ __forceinline__ void gload16(const u16* g, u16* l){
  __builtin_amdgcn_global_load_lds(
      (const __attribute__((address_space(1))) void*)g,
      (__attribute__((address_space(3))) void*)l, 16, 0, 0);
}

// ---------------------------------------------------------------------------
// Prep: transpose + cast the 4 weight matrices (768x768 f32, row-major [K][N])
// into bf16 [N][K].
// ---------------------------------------------------------------------------
__global__ __launch_bounds__(256,1) void prep_w_kernel(
    const float* __restrict__ Wq, const float* __restrict__ Wk,
    const float* __restrict__ Wv, const float* __restrict__ Wo,
    u16* __restrict__ WT)
{
  int bx = blockIdx.x;
  int m  = bx / 144, t = bx % 144;
  int tr = t / 12,  tc = t % 12;
  const float* W = (m==0)?Wq : (m==1)?Wk : (m==2)?Wv : Wo;
  u16* dst = WT + (size_t)m * EE * EE;
  __shared__ float tile[64][65];
  int tid = threadIdx.x;
#pragma unroll
  for (int i=0;i<16;i++){
    int idx = tid + 256*i; int r = idx>>6, c = idx&63;
    tile[r][c] = W[(size_t)(tr*64+r)*EE + tc*64 + c];
  }
  __syncthreads();
#pragma unroll
  for (int i=0;i<16;i++){
    int idx = tid + 256*i; int r = idx>>6, c = idx&63;
    dst[(size_t)(tc*64+r)*EE + tr*64 + c] = f2bf(tile[c][r]);
  }
}

// ---------------------------------------------------------------------------
// Prep TE: TEb[128][768] bf16 (label rows, zero rows >=100) for scores B-frags;
//          TEt[768][128] bf16 (transposed, zero cols >=100) for fle GEMM.
// ---------------------------------------------------------------------------
__global__ __launch_bounds__(128,1) void prep_te_kernel(
    const float* __restrict__ TE, u16* __restrict__ TEb, u16* __restrict__ TEt)
{
  int e   = blockIdx.x;
  int tid = threadIdx.x;
  u16 v = 0;
  if (tid < LL) v = f2bf(TE[(size_t)tid*EE + e]);
  TEt[(size_t)e*128 + tid] = v;
  if (e < 128){
#pragma unroll
    for (int k=tid; k<EE; k+=128)
      TEb[(size_t)e*EE + k] = (e < LL) ? f2bf(TE[(size_t)e*EE + k]) : (u16)0;
  }
}

// ---------------------------------------------------------------------------
// K1: label scores + softmax via MFMA (unchanged).
// ---------------------------------------------------------------------------
__global__ __launch_bounds__(128,4) void label_scores_kernel(
    const float* __restrict__ X, const u16* __restrict__ TEb,
    float* __restrict__ scores_out, u16* __restrict__ att)
{
  __shared__ u16 Xc[32*72];
  __shared__ u16 TEc[112*72];
  const float LOG2E = 1.44269504f;
  int m0 = blockIdx.x * 32;
  int tid = threadIdx.x, lane = tid & 63, w = tid >> 6;
  int l15 = lane & 15, g = lane >> 4;

  f32x4 s[7] = {};
  for (int k0=0; k0<EE; k0+=64){
    __syncthreads();
#pragma unroll
    for (int u=0;u<2;u++){
      int unit = tid + u*128;
      int row = unit >> 3, c8 = (unit & 7) << 3;
      const float* src = &X[(size_t)(m0+row)*EE + k0 + c8];
      float4 a = *(const float4*)src, b = *(const float4*)(src+4);
      u16x8 o;
      o[0]=f2bf(a.x); o[1]=f2bf(a.y); o[2]=f2bf(a.z); o[3]=f2bf(a.w);
      o[4]=f2bf(b.x); o[5]=f2bf(b.y); o[6]=f2bf(b.z); o[7]=f2bf(b.w);
      *(u16x8*)&Xc[row*72 + c8] = o;
    }
#pragma unroll
    for (int u=0;u<7;u++){
      int unit = tid + u*128;
      int l = unit >> 3, c8 = (unit & 7) << 3;
      *(u16x8*)&TEc[l*72 + c8] = *(const u16x8*)&TEb[(size_t)l*EE + k0 + c8];
    }
    __syncthreads();
    bf16x8 af0 = *(const bf16x8*)&Xc[(w*16 + l15)*72 + g*8];
    bf16x8 af1 = *(const bf16x8*)&Xc[(w*16 + l15)*72 + 32 + g*8];
#pragma unroll
    for (int nt=0;nt<7;nt++){
      bf16x8 b0 = *(const bf16x8*)&TEc[(nt*16 + l15)*72 + g*8];
      bf16x8 b1 = *(const bf16x8*)&TEc[(nt*16 + l15)*72 + 32 + g*8];
      s[nt] = __builtin_amdgcn_mfma_f32_16x16x32_bf16(af0, b0, s[nt], 0,0,0);
      s[nt] = __builtin_amdgcn_mfma_f32_16x16x32_bf16(af1, b1, s[nt], 0,0,0);
    }
  }

  int rowb = m0 + w*16 + g*4;
#pragma unroll
  for (int nt=0;nt<7;nt++){
    int col = nt*16 + l15;
    if (col < LL){
#pragma unroll
      for (int r=0;r<4;r++)
        scores_out[(size_t)(rowb + r)*LL + col] = s[nt][r];
    }
  }
  if (l15 >= 4){
#pragma unroll
    for (int r=0;r<4;r++) s[6][r] = -1e30f;
  }
  float inv[4];
#pragma unroll
  for (int r=0;r<4;r++){
    float tm = s[0][r];
#pragma unroll
    for (int nt=1;nt<7;nt++) tm = fmaxf(tm, s[nt][r]);
    tm = fmaxf(tm, __shfl_xor(tm, 1, 16));
    tm = fmaxf(tm, __shfl_xor(tm, 2, 16));
    tm = fmaxf(tm, __shfl_xor(tm, 4, 16));
    tm = fmaxf(tm, __shfl_xor(tm, 8, 16));
    float ps = 0.f;
#pragma unroll
    for (int nt=0;nt<7;nt++){
      float p = exp2f((s[nt][r] - tm) * LOG2E);
      s[nt][r] = p; ps += p;
    }
    ps += __shfl_xor(ps, 1, 16);
    ps += __shfl_xor(ps, 2, 16);
    ps += __shfl_xor(ps, 4, 16);
    ps += __shfl_xor(ps, 8, 16);
    inv[r] = 1.f/ps;
  }
#pragma unroll
  for (int nt=0;nt<7;nt++){
    int col = nt*16 + l15;
#pragma unroll
    for (int r=0;r<4;r++)
      att[(size_t)(rowb + r)*128 + col] = f2bf(s[nt][r] * inv[r]);
  }
  {
    int col = 112 + l15;
#pragma unroll
    for (int r=0;r<4;r++) att[(size_t)(rowb + r)*128 + col] = 0;
  }
}

// ---------------------------------------------------------------------------
// fle GEMM (K=128, reg-staged; epilogue: HT = bf16(X+acc), HU = bf16(X+tp)).
// ---------------------------------------------------------------------------
__global__ __launch_bounds__(256,1) void gemm_fle_kernel(
    const u16* __restrict__ A, const u16* __restrict__ BTw,
    const float* __restrict__ Xf, const float* __restrict__ tp,
    u16* __restrict__ HT, u16* __restrict__ HU, int N, int K)
{
  __shared__ u16 As[128*40];
  __shared__ u16 Bs[128*40];
  int nb = N >> 7;
  int m0 = (blockIdx.x / nb) << 7;
  int n0 = (blockIdx.x % nb) << 7;
  int tid  = threadIdx.x, lane = tid & 63, w = tid >> 6;
  int wm = (w >> 1) << 6, wn = (w & 1) << 6;
  int lr = lane & 15, lk = (lane >> 4) << 3;

  f32x4 acc[4][4] = {};

  for (int k0 = 0; k0 < K; k0 += 32){
    __syncthreads();
#pragma unroll
    for (int i=0;i<2;i++){
      int idx = tid + (i<<8);
      int row = idx >> 2, kq = (idx & 3) << 3;
      *(u16x8*)&As[row*40 + kq] = *(const u16x8*)&A  [(size_t)(m0+row)*K + k0 + kq];
      *(u16x8*)&Bs[row*40 + kq] = *(const u16x8*)&BTw[(size_t)(n0+row)*K + k0 + kq];
    }
    __syncthreads();
    bf16x8 af[4], bfr[4];
#pragma unroll
    for (int i=0;i<4;i++) af [i] = *(const bf16x8*)&As[(wm + i*16 + lr)*40 + lk];
#pragma unroll
    for (int j=0;j<4;j++) bfr[j] = *(const bf16x8*)&Bs[(wn + j*16 + lr)*40 + lk];
#pragma unroll
    for (int i=0;i<4;i++)
#pragma unroll
      for (int j=0;j<4;j++)
        acc[i][j] = __builtin_amdgcn_mfma_f32_16x16x32_bf16(af[i], bfr[j], acc[i][j], 0, 0, 0);
  }

  int rbase = (lane >> 4) << 2;
#pragma unroll
  for (int j=0;j<4;j++){
    int col = n0 + wn + j*16 + lr;
    float tpv = tp[col];
#pragma unroll
    for (int i=0;i<4;i++){
#pragma unroll
      for (int r=0;r<4;r++){
        int row = m0 + wm + i*16 + rbase + r;
        float x = Xf[(size_t)row*EE + col];
        HT[(size_t)row*EE + col] = f2bf(x + acc[i][j][r]);
        HU[(size_t)row*EE + col] = f2bf(x + tpv);
      }
    }
  }
}

// ---------------------------------------------------------------------------
// gemm2: m97-class bf16 GEMM. 128x128 tile, BK=64, 4 waves (2x2), 16x16x32.
// Staging: global_load_lds width=16 (DMA), LINEAR LDS dest; T2 swizzle done by
// pre-swizzling the per-lane GLOBAL source (rule #21: both-sides-or-neither):
//   LDS[row][slot] = G[row][slot ^ (row&7)]   (slot = 8-u16 chunk index)
//   staging lane: row = lane>>3, fetches chunk (lane&7)^(lane>>3)
//   frag read: slot = (kk*4+g) ^ (l15&7)  -> per-quarter 32 banks, 2-way = free
// XCD-chunked blockIdx swizzle (T1): logical tiles n-fastest, so same-m blocks
// (sharing the 192KB A-panel) land on one XCD's L2.
// FUSED=1: QKV in one dispatch, NB=18 (nb/6 selects Q|K|V, Q reads A0=HU).
// FUSED=0: single GEMM (O-projection), NB=6.
// ---------------------------------------------------------------------------
template<int NB, int FUSED>
__global__ __launch_bounds__(256,2) void gemm2_kernel(
    const u16* __restrict__ A0, const u16* __restrict__ A1,
    const u16* __restrict__ Wb,
    const float* __restrict__ b0, const float* __restrict__ b1,
    const float* __restrict__ b2,
    u16* __restrict__ C0, u16* __restrict__ C1, u16* __restrict__ C2)
{
  __shared__ u16 As[128*64];
  __shared__ u16 Bs[128*64];
  const int K = EE;

  int nwg = gridDim.x;
  int bid = blockIdx.x;
  int cpx = nwg >> 3;                       // grid % 8 == 0 (1152 / 384)
  int swz = (bid & 7) * cpx + (bid >> 3);
  int mb = swz / NB, nb = swz % NB;
  int m0 = mb << 7;
  int n0 = (FUSED ? (nb % 6) : nb) << 7;

  const u16* Ap; const u16* Wp; const float* bp; u16* Cp;
  if (!FUSED){ Ap = A0; Wp = Wb; bp = b0; Cp = C0; }
  else {
    int which = nb / 6;
    if (which == 0){ Ap = A0; Wp = Wb;                      bp = b0; Cp = C0; }
    else if (which == 1){ Ap = A1; Wp = Wb + (size_t)EE*EE; bp = b1; Cp = C1; }
    else { Ap = A1; Wp = Wb + 2*(size_t)EE*EE;              bp = b2; Cp = C2; }
  }

  int tid = threadIdx.x, lane = tid & 63, w = tid >> 6;
  int wm = (w >> 1) << 6, wn = (w & 1) << 6;
  int lr = lane & 15, g = lane >> 4;
  int lrow = lane >> 3;
  int lchunk = (lane & 7) ^ lrow;           // pre-swizzled source chunk

  f32x4 acc[4][4] = {};

  for (int k0 = 0; k0 < K; k0 += 64){
    __syncthreads();
#pragma unroll
    for (int t=0;t<4;t++){
      int r0 = w*32 + t*8;                  // wave-uniform LDS base
      gload16(&Ap[(size_t)(m0 + r0 + lrow)*K + k0 + (lchunk<<3)], &As[r0*64]);
      gload16(&Wp[(size_t)(n0 + r0 + lrow)*K + k0 + (lchunk<<3)], &Bs[r0*64]);
    }
    __syncthreads();                        // compiler drains vmcnt(0) here
#pragma unroll
    for (int kk=0;kk<2;kk++){
      int cs = ((kk<<2) + g) ^ (lr & 7);
      bf16x8 af[4], bfr[4];
#pragma unroll
      for (int i=0;i<4;i++) af [i] = *(const bf16x8*)&As[(wm + i*16 + lr)*64 + (cs<<3)];
#pragma unroll
      for (int j=0;j<4;j++) bfr[j] = *(const bf16x8*)&Bs[(wn + j*16 + lr)*64 + (cs<<3)];
#pragma unroll
      for (int i=0;i<4;i++)
#pragma unroll
        for (int j=0;j<4;j++)
          acc[i][j] = __builtin_amdgcn_mfma_f32_16x16x32_bf16(af[i], bfr[j], acc[i][j], 0, 0, 0);
    }
  }

  int rbase = (lane >> 4) << 2;
#pragma unroll
  for (int j=0;j<4;j++){
    int col = n0 + wn + j*16 + lr;
    float bv = bp[col];
#pragma unroll
    for (int i=0;i<4;i++){
#pragma unroll
      for (int r=0;r<4;r++){
        int row = m0 + wm + i*16 + rbase + r;
        Cp[(size_t)row*EE + col] = f2bf(acc[i][j][r] + bv);
      }
    }
  }
}

// ---------------------------------------------------------------------------
// K4: MFMA flash attention (unchanged this round; swapped-QK rewrite next).
// ---------------------------------------------------------------------------
__global__ __launch_bounds__(256,3) void attn_mfma_kernel(
    const u16* __restrict__ Q, const u16* __restrict__ K,
    const u16* __restrict__ V, const float* __restrict__ mask,
    u16* __restrict__ CTX)
{
  __shared__ u16 Ks[64*72];
  __shared__ u16 VT[64*72];
  __shared__ u16 Pl[4][32*72];
  __shared__ float MB[64];

  const float LOG2E = 1.44269504f;
  int bx = blockIdx.x;
  int bh = bx >> 2, q0 = (bx & 3) << 7;
  int b = bh / HH, h = bh % HH;
  int tid = threadIdx.x, lane = tid & 63, w = tid >> 6;
  int l15 = lane & 15, g = lane >> 4;
  int wq0 = q0 + w*32;
  size_t rowbase = (size_t)b*TT;
  u16* pw = &Pl[w][0];

  bf16x8 qf[2][2];
#pragma unroll
  for (int i=0;i<2;i++)
#pragma unroll
    for (int kk=0;kk<2;kk++)
      qf[i][kk] = *(const bf16x8*)&Q[(rowbase + wq0 + i*16 + l15)*EE + h*DD + kk*32 + g*8];

  f32x4 ctxf[2][4] = {};
  float mrun[2][4], lrun[2][4];
#pragma unroll
  for (int i=0;i<2;i++)
#pragma unroll
    for (int r=0;r<4;r++){ mrun[i][r] = -1e30f; lrun[i][r] = 0.f; }

  for (int k0=0; k0<TT; k0+=64){
    __syncthreads();
#pragma unroll
    for (int u=0;u<2;u++){
      int unit = tid + (u<<8);
      int row = unit >> 3, c8 = (unit & 7) << 3;
      size_t gsrc = (rowbase + k0 + row)*EE + h*DD + c8;
      u16x8 kv = *(const u16x8*)&K[gsrc];
      u16x8 vv = *(const u16x8*)&V[gsrc];
      *(u16x8*)&Ks[row*72 + c8] = kv;
      int kb8 = row >> 3, k7 = row & 7;
#pragma unroll
      for (int e=0;e<8;e++){
        int d = c8 + e;
        VT[d*72 + ((kb8 ^ ((d>>3)&7))<<3) + k7] = vv[e];
      }
    }
    if (tid < 64) MB[tid] = (1.0f - mask[b*TT + k0 + tid]) * (-1e9f * LOG2E);
    __syncthreads();

    f32x4 s[2][4] = {};
#pragma unroll
    for (int kb=0;kb<4;kb++){
      bf16x8 kf0 = *(const bf16x8*)&Ks[(kb*16 + l15)*72 + g*8];
      bf16x8 kf1 = *(const bf16x8*)&Ks[(kb*16 + l15)*72 + 32 + g*8];
#pragma unroll
      for (int i=0;i<2;i++){
        s[i][kb] = __builtin_amdgcn_mfma_f32_16x16x32_bf16(qf[i][0], kf0, s[i][kb], 0,0,0);
        s[i][kb] = __builtin_amdgcn_mfma_f32_16x16x32_bf16(qf[i][1], kf1, s[i][kb], 0,0,0);
      }
    }

    const float QSC = 0.125f * LOG2E;
#pragma unroll
    for (int i=0;i<2;i++)
#pragma unroll
      for (int kb=0;kb<4;kb++){
        float mb = MB[kb*16 + l15];
#pragma unroll
        for (int r=0;r<4;r++) s[i][kb][r] = s[i][kb][r]*QSC + mb;
      }
    if ((k0 < wq0 + 32) && (k0 + 64 > wq0)){
#pragma unroll
      for (int i=0;i<2;i++){
        int qr = wq0 + i*16 + g*4;
#pragma unroll
        for (int kb=0;kb<4;kb++){
          int kpos = k0 + kb*16 + l15;
#pragma unroll
          for (int r=0;r<4;r++)
            if (kpos == qr + r) s[i][kb][r] -= 1e9f*LOG2E;
        }
      }
    }

#pragma unroll
    for (int i=0;i<2;i++){
#pragma unroll
      for (int r=0;r<4;r++){
        float tm = fmaxf(fmaxf(s[i][0][r], s[i][1][r]), fmaxf(s[i][2][r], s[i][3][r]));
        tm = fmaxf(tm, __shfl_xor(tm, 1, 16));
        tm = fmaxf(tm, __shfl_xor(tm, 2, 16));
        tm = fmaxf(tm, __shfl_xor(tm, 4, 16));
        tm = fmaxf(tm, __shfl_xor(tm, 8, 16));
        float mold = mrun[i][r];
        float mnew = fmaxf(mold, tm);
        float sc = exp2f(mold - mnew);
        mrun[i][r] = mnew;
        float ps = 0.f;
#pragma unroll
        for (int kb=0;kb<4;kb++){
          float p = exp2f(s[i][kb][r] - mnew);
          s[i][kb][r] = p;
          ps += p;
        }
        lrun[i][r] = lrun[i][r]*sc + ps;
#pragma unroll
        for (int dj=0;dj<4;dj++) ctxf[i][dj][r] *= sc;
      }
    }

#pragma unroll
    for (int i=0;i<2;i++)
#pragma unroll
      for (int kb=0;kb<4;kb++)
#pragma unroll
        for (int r=0;r<4;r++)
          pw[(i*16 + g*4 + r)*72 + kb*16 + l15] = f2bf(s[i][kb][r]);

    bf16x8 pa[2][2];
#pragma unroll
    for (int i=0;i<2;i++)
#pragma unroll
      for (int kk=0;kk<2;kk++)
        pa[i][kk] = *(const bf16x8*)&pw[(i*16 + l15)*72 + kk*32 + g*8];

#pragma unroll
    for (int dj=0;dj<4;dj++){
      int d = dj*16 + l15;
      int dsw = (d>>3)&7;
      bf16x8 v0 = *(const bf16x8*)&VT[d*72 + (((g  ) ^ dsw)<<3)];
      bf16x8 v1 = *(const bf16x8*)&VT[d*72 + (((g+4) ^ dsw)<<3)];
#pragma unroll
      for (int i=0;i<2;i++){
        ctxf[i][dj] = __builtin_amdgcn_mfma_f32_16x16x32_bf16(pa[i][0], v0, ctxf[i][dj], 0,0,0);
        ctxf[i][dj] = __builtin_amdgcn_mfma_f32_16x16x32_bf16(pa[i][1], v1, ctxf[i][dj], 0,0,0);
      }
    }
  }

  float inv[2][4];
#pragma unroll
  for (int i=0;i<2;i++)
#pragma unroll
    for (int r=0;r<4;r++){
      float l = lrun[i][r];
      l += __shfl_xor(l, 1, 16);
      l += __shfl_xor(l, 2, 16);
      l += __shfl_xor(l, 4, 16);
      l += __shfl_xor(l, 8, 16);
      inv[i][r] = 1.0f / l;
    }
#pragma unroll
  for (int i=0;i<2;i++)
#pragma unroll
    for (int dj=0;dj<4;dj++)
#pragma unroll
      for (int r=0;r<4;r++)
        pw[(i*16 + g*4 + r)*64 + dj*16 + l15] = f2bf(ctxf[i][dj][r] * inv[i][r]);
#pragma unroll
  for (int t=0;t<4;t++){
    int row = lane >> 1, c = ((lane & 1)<<5) + t*8;
    *(u16x8*)&CTX[(rowbase + wq0 + row)*EE + h*DD + c] = *(const u16x8*)&pw[row*64 + c];
  }
}

// ---------------------------------------------------------------------------
// K5: LayerNorm(attn_out + h_unknown)*g + b + h_truth -> out (f32)
// ---------------------------------------------------------------------------
__global__ __launch_bounds__(256,1) void ln_out_kernel(
    const u16* __restrict__ AO, const u16* __restrict__ HU,
    const u16* __restrict__ HT, const float* __restrict__ g,
    const float* __restrict__ bta, float* __restrict__ out)
{
  __shared__ float red[4];
  int r = blockIdx.x, tid = threadIdx.x;
  size_t base = (size_t)r*EE;
  float x[3];
#pragma unroll
  for (int j=0;j<3;j++){
    int e = tid + j*256;
    x[j] = bf2f(AO[base+e]) + bf2f(HU[base+e]);
  }
  float s = x[0]+x[1]+x[2];
#pragma unroll
  for (int o=32;o;o>>=1) s += __shfl_xor(s, o, 64);
  int w = tid>>6;
  if ((tid&63)==0) red[w] = s;
  __syncthreads();
  float mu = (red[0]+red[1]+red[2]+red[3]) * (1.0f/EE);
  __syncthreads();
  float d2 = 0.f;
#pragma unroll
  for (int j=0;j<3;j++){ float d = x[j]-mu; d2 += d*d; }
#pragma unroll
  for (int o=32;o;o>>=1) d2 += __shfl_xor(d2, o, 64);
  if ((tid&63)==0) red[w] = d2;
  __syncthreads();
  float var = (red[0]+red[1]+red[2]+red[3]) * (1.0f/EE);
  float rs = rsqrtf(var + 1e-12f);
#pragma unroll
  for (int j=0;j<3;j++){
    int e = tid + j*256;
    out[base+e] = (x[j]-mu)*rs*g[e] + bta[e] + bf2f(HT[base+e]);
  }
}

// ---------------------------------------------------------------------------
extern "C" void kernel_launch(void* const* d_in, const int* in_sizes, int n_in,
                              void* d_out, int out_size, void* d_ws, size_t ws_size,
                              hipStream_t stream)
{
  (void)in_sizes; (void)n_in; (void)out_size; (void)ws_size;
  const float* X    = (const float*)d_in[0];
  const float* mask = (const float*)d_in[1];
  const float* TE   = (const float*)d_in[2];
  const float* tp   = (const float*)d_in[3];
  const float* Wq   = (const float*)d_in[4];
  const float* bq   = (const float*)d_in[5];
  const float* Wk   = (const float*)d_in[6];
  const float* bk   = (const float*)d_in[7];
  const float* Wv   = (const float*)d_in[8];
  const float* bv   = (const float*)d_in[9];
  const float* Wo   = (const float*)d_in[10];
  const float* bo   = (const float*)d_in[11];
  const float* ln_g = (const float*)d_in[12];
  const float* ln_b = (const float*)d_in[13];

  float* out    = (float*)d_out;
  float* scores = out + BTE;

  char* ws = (char*)d_ws;
  const size_t BF = BTE*2;           // bytes of one [BT][E] bf16 buffer
  u16* HT   = (u16*)(ws);
  u16* HU   = (u16*)(ws + BF);
  u16* WT   = (u16*)(ws + 2*BF);     // 4 x [768][768] bf16 (transposed)
  u16* Qb   = (u16*)(ws + 2*BF + (size_t)4*EE*EE*2);
  u16* Kb   = Qb  + BTE;
  u16* Vb   = Kb  + BTE;
  u16* CTXb = Vb  + BTE;
  u16* AOb  = CTXb + BTE;
  u16* ATT  = AOb + BTE;                       // [8192][128] bf16
  u16* TEb  = ATT + (size_t)BT*128;            // [128][768] bf16
  u16* TEt  = TEb + (size_t)128*EE;            // [768][128] bf16

  prep_w_kernel <<<dim3(576), dim3(256), 0, stream>>>(Wq, Wk, Wv, Wo, WT);
  prep_te_kernel<<<dim3(768), dim3(128), 0, stream>>>(TE, TEb, TEt);

  label_scores_kernel<<<dim3(BT/32), dim3(128), 0, stream>>>(X, TEb, scores, ATT);

  // fle GEMM + fused HT/HU epilogue: M=8192, N=768, K=128
  gemm_fle_kernel<<<dim3((BT/128)*(EE/128)), dim3(256), 0, stream>>>(
      ATT, TEt, X, tp, HT, HU, EE, 128);

  // fused QKV projections: 64 m-blocks x 18 n-blocks
  gemm2_kernel<18,1><<<dim3(64*18), dim3(256), 0, stream>>>(
      HU, HT, WT, bq, bk, bv, Qb, Kb, Vb);

  attn_mfma_kernel<<<dim3(BB*HH*4), dim3(256), 0, stream>>>(Qb, Kb, Vb, mask, CTXb);

  // O projection: 64 x 6
  gemm2_kernel<6,0><<<dim3(64*6), dim3(256), 0, stream>>>(
      CTXb, nullptr, WT + 3*(size_t)EE*EE, bo, nullptr, nullptr, AOb, nullptr, nullptr);

  ln_out_kernel<<<dim3(BT), dim3(256), 0, stream>>>(AOb, HU, HT, ln_g, ln_b, out);
}